// Round 1
// baseline (18032.759 us; speedup 1.0000x reference)
//
#include <hip/hip_runtime.h>
#include <hip/hip_bf16.h>

// ============================================================================
// RecurrentDecoder: persistent cooperative kernel, 2 grid barriers per step.
//   P0  : precompute amax/amin over t, bf16 weight copies, shifted dec seq,
//         zero h.
//   loop s=0..64:
//     PX : blocks 0..31  -> per-b attention (proj, sden, tw, ctx)  [s<64]
//          blocks 32..43 -> mel/gate MFMA for step s-1             [s>=1]
//     bar
//     PY : blocks 0..63 wave0 -> fused gh+gi MFMA (96 mfma) + GRU pointwise
//     bar
// Double buffers: hbf[2], ctxb[2] (parity s&1).
// ============================================================================

#define LOG2E 1.4426950408889634f
#define BAR_MAGIC 0x13572468u

typedef __attribute__((ext_vector_type(8))) short bf8;     // 8 x bf16 (4 VGPR)
typedef __attribute__((ext_vector_type(4))) float f32x4;

struct Params {
  const float* dec;    // [64][32][256]
  const float* ali;    // [256][32][256]
  const float* watt;   // [256][512]
  const float* wih;    // [1536][512]
  const float* whh;    // [1536][512]
  const float* wmel;   // [80][768]
  const float* bmel;   // [80]
  const float* wgate;  // [768]
  const float* bgate;  // [1]
  float* out;          // mel 32*80*64 then gate 32*64
  unsigned* bar;       // [0]=cnt [1]=gen [2]=init-flag
  float* amax;         // [32][256]
  float* amin;         // [32][256]
  __hip_bfloat16* wihb;    // [1536][512]
  __hip_bfloat16* whhb;    // [1536][512]
  __hip_bfloat16* wmelgb;  // [96][768] rows0..79=Wmel,80=Wgate,81..95=0
  __hip_bfloat16* seqb;    // [64][32][256] shifted dec inputs
  __hip_bfloat16* hbf;     // [2][32][512]
  __hip_bfloat16* ctxb;    // [2][32][256]
  float* hf;               // [32][512]
};

__device__ __forceinline__ bf8 ldfrag(const __hip_bfloat16* p) {
  return *(const bf8*)p;
}
__device__ __forceinline__ float sigm(float x) {
  return 1.0f / (1.0f + exp2f(-x * LOG2E));
}
__device__ __forceinline__ float tanhfast(float x) {
  x = fminf(fmaxf(x, -15.0f), 15.0f);
  float e = exp2f(x * (2.0f * LOG2E));
  return (e - 1.0f) / (e + 1.0f);
}

// Device-scope sense-reversing grid barrier. All 256 blocks must call it the
// same number of times. Acquire/release at AGENT scope handles cross-XCD L2.
__device__ __forceinline__ void gbar(unsigned* cnt, unsigned* gen) {
  __syncthreads();                    // drains vmcnt: block's stores are in L2
  if (threadIdx.x == 0) {
    __threadfence();                  // make block's writes device-visible
    unsigned g = __hip_atomic_load(gen, __ATOMIC_RELAXED, __HIP_MEMORY_SCOPE_AGENT);
    unsigned old = __hip_atomic_fetch_add(cnt, 1u, __ATOMIC_ACQ_REL, __HIP_MEMORY_SCOPE_AGENT);
    if (old == 255u) {
      __hip_atomic_store(cnt, 0u, __ATOMIC_RELAXED, __HIP_MEMORY_SCOPE_AGENT);
      __hip_atomic_store(gen, g + 1u, __ATOMIC_RELEASE, __HIP_MEMORY_SCOPE_AGENT);
    } else {
      while (__hip_atomic_load(gen, __ATOMIC_ACQUIRE, __HIP_MEMORY_SCOPE_AGENT) == g)
        __builtin_amdgcn_s_sleep(2);
    }
  }
  __syncthreads();
}

__global__ void __launch_bounds__(256) rdec_kernel(Params p) {
  const int tid = threadIdx.x;
  const int bid = blockIdx.x;
  unsigned* cnt = p.bar + 0;
  unsigned* gen = p.bar + 1;
  unsigned* fl  = p.bar + 2;

  __shared__ float shp[256], shm[256], shr[256], shtw[256];

  // ---- barrier state init handshake (ws is poisoned 0xAA each launch) ----
  if (bid == 0 && tid == 0) {
    __hip_atomic_store(cnt, 0u, __ATOMIC_RELAXED, __HIP_MEMORY_SCOPE_AGENT);
    __hip_atomic_store(gen, 0u, __ATOMIC_RELAXED, __HIP_MEMORY_SCOPE_AGENT);
    __hip_atomic_store(fl, BAR_MAGIC, __ATOMIC_RELEASE, __HIP_MEMORY_SCOPE_AGENT);
  }
  if (tid == 0) {
    while (__hip_atomic_load(fl, __ATOMIC_ACQUIRE, __HIP_MEMORY_SCOPE_AGENT) != BAR_MAGIC)
      __builtin_amdgcn_s_sleep(1);
  }
  __syncthreads();

  // ---------------------------- P0: precompute ----------------------------
  if (bid < 32) {
    // amax/amin over t for each (b,e)
    int g = bid * 256 + tid;
    int b = g >> 8, e = g & 255;
    const float* a0 = p.ali + b * 256 + e;
    float mx = -1e30f, mn = 1e30f;
    for (int t = 0; t < 256; ++t) {
      float a = a0[t * 8192];
      mx = fmaxf(mx, a);
      mn = fminf(mn, a);
    }
    p.amax[g] = mx;
    p.amin[g] = mn;
  } else if (bid < 96) {
    int g = (bid - 32) * 256 + tid;
    for (int i = g; i < 1536 * 512; i += 16384) p.wihb[i] = __float2bfloat16(p.wih[i]);
  } else if (bid < 160) {
    int g = (bid - 96) * 256 + tid;
    for (int i = g; i < 1536 * 512; i += 16384) p.whhb[i] = __float2bfloat16(p.whh[i]);
  } else if (bid < 192) {
    int g = (bid - 160) * 256 + tid;
    for (int i = g; i < 64 * 32 * 256; i += 8192) {
      int s = i >> 13;  // /8192
      float v = (s == 0) ? 0.0f : p.dec[(s - 1) * 8192 + (i & 8191)];
      p.seqb[i] = __float2bfloat16(v);
    }
  } else if (bid < 224) {
    int g = (bid - 192) * 256 + tid;
    for (int i = g; i < 96 * 768; i += 8192) {
      int r = i / 768, c = i % 768;
      float v = (r < 80) ? p.wmel[i] : ((r == 80) ? p.wgate[c] : 0.0f);
      p.wmelgb[i] = __float2bfloat16(v);
    }
  } else if (bid < 232) {
    int g = (bid - 224) * 256 + tid;
    for (int i = g; i < 32 * 512; i += 2048) {
      p.hf[i] = 0.0f;
      p.hbf[i] = __float2bfloat16(0.0f);  // hbf parity 0
    }
  }
  gbar(cnt, gen);

  // ------------------------------ main loop -------------------------------
  for (int s = 0; s <= 64; ++s) {
    // ---------------- PX: attention (blocks 0..31) ----------------
    if (s < 64 && bid < 32) {
      const int b = bid;
      // pass 1: proj[e] (fp32) + softmax denominator over t
      {
        int e = tid;
        const float4* w4 = (const float4*)(p.watt + e * 512);
        const float4* h4 = (const float4*)(p.hf + b * 512);
        float acc = 0.0f;
#pragma unroll 4
        for (int k = 0; k < 128; ++k) {
          float4 w = w4[k], h = h4[k];
          acc += w.x * h.x + w.y * h.y + w.z * h.z + w.w * h.w;
        }
        float pe = acc;
        float m = (pe >= 0.0f) ? pe * p.amax[b * 256 + e] : pe * p.amin[b * 256 + e];
        float p2 = pe * LOG2E, m2 = m * LOG2E;
        shp[e] = p2;
        shm[e] = m2;
        const float* a0 = p.ali + b * 256 + e;
        float s0 = 0, s1 = 0, s2 = 0, s3 = 0;
        for (int t = 0; t < 256; t += 4) {
          s0 += exp2f(fmaf(a0[(t + 0) * 8192], p2, -m2));
          s1 += exp2f(fmaf(a0[(t + 1) * 8192], p2, -m2));
          s2 += exp2f(fmaf(a0[(t + 2) * 8192], p2, -m2));
          s3 += exp2f(fmaf(a0[(t + 3) * 8192], p2, -m2));
        }
        shr[e] = 1.0f / ((s0 + s1) + (s2 + s3));
      }
      __syncthreads();
      // pass 2: tw[t] = sum_e w[t,e]
      {
        int t = tid;
        const float4* a4 = (const float4*)(p.ali + (t * 32 + b) * 256);
        float acc = 0.0f;
        for (int e4 = 0; e4 < 64; ++e4) {
          float4 a = a4[e4];
          float4 pp = ((const float4*)shp)[e4];
          float4 mm = ((const float4*)shm)[e4];
          float4 rr = ((const float4*)shr)[e4];
          acc += exp2f(fmaf(a.x, pp.x, -mm.x)) * rr.x;
          acc += exp2f(fmaf(a.y, pp.y, -mm.y)) * rr.y;
          acc += exp2f(fmaf(a.z, pp.z, -mm.z)) * rr.z;
          acc += exp2f(fmaf(a.w, pp.w, -mm.w)) * rr.w;
        }
        shtw[t] = acc;
      }
      __syncthreads();
      // pass 3: ctx[e] = sum_t tw[t]*a[t,b,e]  -> bf16 double buffer
      {
        int e = tid;
        const float* a0 = p.ali + b * 256 + e;
        float c0 = 0, c1 = 0, c2 = 0, c3 = 0;
        for (int t = 0; t < 256; t += 4) {
          c0 += shtw[t + 0] * a0[(t + 0) * 8192];
          c1 += shtw[t + 1] * a0[(t + 1) * 8192];
          c2 += shtw[t + 2] * a0[(t + 2) * 8192];
          c3 += shtw[t + 3] * a0[(t + 3) * 8192];
        }
        p.ctxb[(s & 1) * 8192 + b * 256 + e] = __float2bfloat16((c0 + c1) + (c2 + c3));
      }
    } else if (s >= 1 && bid >= 32 && bid < 44 && tid < 64) {
      // ---------------- PX: mel/gate for step s-1 (MFMA) ----------------
      int tile = bid - 32;  // 12 tiles: mt(2) x nt(6)
      int mt = tile & 1, nt = tile >> 1;
      int l = tid, lm = l & 15, lq = l >> 4;
      const __hip_bfloat16* ctxp = p.ctxb + ((s - 1) & 1) * 8192;
      const __hip_bfloat16* hb = p.hbf + (s & 1) * 16384;
      int am = mt * 16 + lm;   // A row (batch)
      int bn = nt * 16 + lm;   // B row (output col of [96][768])
      f32x4 acc = {0.f, 0.f, 0.f, 0.f};
#pragma unroll
      for (int kt = 0; kt < 24; ++kt) {
        bf8 a = (kt < 8) ? ldfrag(ctxp + am * 256 + kt * 32 + lq * 8)
                         : ldfrag(hb + am * 512 + (kt - 8) * 32 + lq * 8);
        bf8 bb = ldfrag(p.wmelgb + bn * 768 + kt * 32 + lq * 8);
        acc = __builtin_amdgcn_mfma_f32_16x16x32_bf16(a, bb, acc, 0, 0, 0);
      }
      int t_out = s - 1;
#pragma unroll
      for (int r = 0; r < 4; ++r) {
        int b = mt * 16 + lq * 4 + r;  // D row = batch
        float v = acc[r];
        if (bn < 80)
          p.out[b * 5120 + bn * 64 + t_out] = v + p.bmel[bn];
        else if (bn == 80)
          p.out[163840 + b * 64 + t_out] = v + p.bgate[0];
      }
    }
    gbar(cnt, gen);

    // ---------------- PY: fused gh + gi MFMA + GRU pointwise ----------------
    if (s < 64) {
      if (bid < 64 && tid < 64) {
        int mt = bid & 1, dt = bid >> 1;
        int l = tid, lm = l & 15, lq = l >> 4;
        int am = mt * 16 + lm;      // A row (batch) for fragments
        int dcol = dt * 16 + lm;    // output d (D col) == W row offset
        const __hip_bfloat16* hb = p.hbf + (s & 1) * 16384;
        const __hip_bfloat16* ctxp = p.ctxb + (s & 1) * 8192;
        const __hip_bfloat16* seqp = p.seqb + s * 8192;
        f32x4 ar = {0.f, 0.f, 0.f, 0.f};
        f32x4 az = ar, ain = ar, ahn = ar;
        // gh = h @ W_hh^T  (K=512): r,z -> ar,az ; n -> ahn (kept separate)
#pragma unroll
        for (int kt = 0; kt < 16; ++kt) {
          bf8 a = ldfrag(hb + am * 512 + kt * 32 + lq * 8);
          bf8 br = ldfrag(p.whhb + (dcol)*512 + kt * 32 + lq * 8);
          bf8 bz = ldfrag(p.whhb + (512 + dcol) * 512 + kt * 32 + lq * 8);
          bf8 bn = ldfrag(p.whhb + (1024 + dcol) * 512 + kt * 32 + lq * 8);
          ar = __builtin_amdgcn_mfma_f32_16x16x32_bf16(a, br, ar, 0, 0, 0);
          az = __builtin_amdgcn_mfma_f32_16x16x32_bf16(a, bz, az, 0, 0, 0);
          ahn = __builtin_amdgcn_mfma_f32_16x16x32_bf16(a, bn, ahn, 0, 0, 0);
        }
        // gi_dec = dec @ W_ih[:, 0:256]^T  (K=256)
#pragma unroll
        for (int kt = 0; kt < 8; ++kt) {
          bf8 a = ldfrag(seqp + am * 256 + kt * 32 + lq * 8);
          bf8 br = ldfrag(p.wihb + (dcol)*512 + kt * 32 + lq * 8);
          bf8 bz = ldfrag(p.wihb + (512 + dcol) * 512 + kt * 32 + lq * 8);
          bf8 bn = ldfrag(p.wihb + (1024 + dcol) * 512 + kt * 32 + lq * 8);
          ar = __builtin_amdgcn_mfma_f32_16x16x32_bf16(a, br, ar, 0, 0, 0);
          az = __builtin_amdgcn_mfma_f32_16x16x32_bf16(a, bz, az, 0, 0, 0);
          ain = __builtin_amdgcn_mfma_f32_16x16x32_bf16(a, bn, ain, 0, 0, 0);
        }
        // gi_ctx = ctx @ W_ih[:, 256:512]^T  (K=256)
#pragma unroll
        for (int kt = 0; kt < 8; ++kt) {
          bf8 a = ldfrag(ctxp + am * 256 + kt * 32 + lq * 8);
          bf8 br = ldfrag(p.wihb + (dcol)*512 + 256 + kt * 32 + lq * 8);
          bf8 bz = ldfrag(p.wihb + (512 + dcol) * 512 + 256 + kt * 32 + lq * 8);
          bf8 bn = ldfrag(p.wihb + (1024 + dcol) * 512 + 256 + kt * 32 + lq * 8);
          ar = __builtin_amdgcn_mfma_f32_16x16x32_bf16(a, br, ar, 0, 0, 0);
          az = __builtin_amdgcn_mfma_f32_16x16x32_bf16(a, bz, az, 0, 0, 0);
          ain = __builtin_amdgcn_mfma_f32_16x16x32_bf16(a, bn, ain, 0, 0, 0);
        }
        // GRU pointwise epilogue in-wave; D layout: row b=(lq*4+r)+mt*16, col d=dcol
        __hip_bfloat16* hbn = p.hbf + ((s + 1) & 1) * 16384;
#pragma unroll
        for (int r = 0; r < 4; ++r) {
          int b = mt * 16 + lq * 4 + r;
          float rg = sigm(ar[r]);
          float zg = sigm(az[r]);
          float nn = tanhfast(fmaf(rg, ahn[r], ain[r]));
          float ho = p.hf[b * 512 + dcol];
          float hn = fmaxf(0.0f, fmaf(zg, ho - nn, nn));  // relu((1-z)n+z*h)
          p.hf[b * 512 + dcol] = hn;
          hbn[b * 512 + dcol] = __float2bfloat16(hn);
        }
      }
      gbar(cnt, gen);
    }
  }
}

extern "C" void kernel_launch(void* const* d_in, const int* in_sizes, int n_in,
                              void* d_out, int out_size, void* d_ws, size_t ws_size,
                              hipStream_t stream) {
  Params P;
  P.dec = (const float*)d_in[0];
  P.ali = (const float*)d_in[1];
  P.watt = (const float*)d_in[2];
  P.wih = (const float*)d_in[3];
  P.whh = (const float*)d_in[4];
  P.wmel = (const float*)d_in[5];
  P.bmel = (const float*)d_in[6];
  P.wgate = (const float*)d_in[7];
  P.bgate = (const float*)d_in[8];
  P.out = (float*)d_out;

  char* w = (char*)d_ws;
  size_t o = 0;
  auto nxt = [&](size_t b) {
    char* r = w + o;
    o += (b + 255) & ~(size_t)255;
    return r;
  };
  P.bar = (unsigned*)nxt(256);
  P.amax = (float*)nxt(32 * 256 * 4);
  P.amin = (float*)nxt(32 * 256 * 4);
  P.wihb = (__hip_bfloat16*)nxt(1536 * 512 * 2);
  P.whhb = (__hip_bfloat16*)nxt(1536 * 512 * 2);
  P.wmelgb = (__hip_bfloat16*)nxt(96 * 768 * 2);
  P.seqb = (__hip_bfloat16*)nxt(64 * 32 * 256 * 2);
  P.hbf = (__hip_bfloat16*)nxt(2 * 32 * 512 * 2);
  P.ctxb = (__hip_bfloat16*)nxt(2 * 32 * 256 * 2);
  P.hf = (float*)nxt(32 * 512 * 4);

  void* args[] = {&P};
  hipError_t err = hipLaunchCooperativeKernel((void*)rdec_kernel, dim3(256), dim3(256),
                                              args, 0, stream);
  if (err != hipSuccess) {
    // fallback: plain launch (grid fits 1 block/CU on 256 CUs -> co-resident)
    rdec_kernel<<<dim3(256), dim3(256), 0, stream>>>(P);
  }
}

// Round 2
// 3087.576 us; speedup vs baseline: 5.8404x; 5.8404x over previous
//
#include <hip/hip_runtime.h>
#include <hip/hip_bf16.h>

// ============================================================================
// RecurrentDecoder v2: 64-block persistent cooperative kernel.
// Fixes vs v1: tree barrier with RELAXED spins (one acquire-inv per block per
// barrier, not per poll), 8-way leaf counters, grid 256->64 blocks,
// bf16 ali + packed-transposed bf16 W_att for the attention phase.
//
//   P0  : blocks 0-31: ali->bf16 + amax/amin (fused);
//         blocks 32-63: bf16 weight copies, packed W_att^T, shifted dec, h=0.
//   loop s=0..64:
//     PX : blocks 0..31  -> per-b attention (proj, den, tw, ctx)   [s<64]
//          blocks 32..43 -> mel/gate MFMA for step s-1             [s>=1]
//     bar
//     PY : blocks 0..31 (2 waves) -> fused gh+gi MFMA + GRU pointwise [s<64]
//     bar
// ============================================================================

#define LOG2E 1.4426950408889634f
#define BAR_MAGIC 0x13572468u

typedef __attribute__((ext_vector_type(8))) short bf8;     // 8 x bf16 (4 VGPR)
typedef __attribute__((ext_vector_type(4))) float f32x4;

struct Params {
  const float* dec;    // [64][32][256]
  const float* ali;    // [256][32][256]
  const float* watt;   // [256][512]
  const float* wih;    // [1536][512]
  const float* whh;    // [1536][512]
  const float* wmel;   // [80][768]
  const float* bmel;   // [80]
  const float* wgate;  // [768]
  const float* bgate;  // [1]
  float* out;          // mel 32*80*64 then gate 32*64
  unsigned* bar;       // [0]=magic, [16]=gen, [32]=root, [48+16i]=leaf i
  float* amax;         // [32][256]
  float* amin;         // [32][256]
  __hip_bfloat16* wihb;    // [1536][512]
  __hip_bfloat16* whhb;    // [1536][512]
  __hip_bfloat16* wmelgb;  // [96][768] rows0..79=Wmel,80=Wgate,81..95=0
  __hip_bfloat16* seqb;    // [64][32][256] shifted dec inputs
  __hip_bfloat16* hbf;     // [2][32][512]
  __hip_bfloat16* ctxb;    // [2][32][256]
  unsigned short* alib;    // [256][32][256] bf16 raw bits
  unsigned* wattp;         // [256][256]: pair (k=2kp lo16, k=2kp+1 hi16) for e
  float* hf;               // [32][512]
};

__device__ __forceinline__ bf8 ldfrag(const __hip_bfloat16* p) {
  return *(const bf8*)p;
}
__device__ __forceinline__ float sigm(float x) {
  return 1.0f / (1.0f + exp2f(-x * LOG2E));
}
__device__ __forceinline__ float tanhfast(float x) {
  x = fminf(fmaxf(x, -15.0f), 15.0f);
  float e = exp2f(x * (2.0f * LOG2E));
  return (e - 1.0f) / (e + 1.0f);
}
__device__ __forceinline__ float btof(unsigned short v) {
  return __uint_as_float(((unsigned)v) << 16);
}
__device__ __forceinline__ unsigned short f2bfbits(float x) {
  __hip_bfloat16 h = __float2bfloat16(x);
  return *(unsigned short*)&h;
}

// Tree grid barrier: monotonic leaf/root counters, RELAXED spin on gen,
// acquire fence once after release observed. All 64 blocks call it equally.
__device__ __forceinline__ void gbar(unsigned* bar, int bid) {
  __syncthreads();  // intra-block + vmcnt drain of this block's stores to L2
  if (threadIdx.x == 0) {
    unsigned* gen = bar + 16;
    unsigned* root = bar + 32;
    unsigned* leaf = bar + 48 + (bid & 7) * 16;
    unsigned g = __hip_atomic_load(gen, __ATOMIC_RELAXED, __HIP_MEMORY_SCOPE_AGENT);
    __builtin_amdgcn_fence(__ATOMIC_RELEASE, "agent");  // publish this block's writes
    bool releaser = false;
    unsigned o = __hip_atomic_fetch_add(leaf, 1u, __ATOMIC_RELAXED, __HIP_MEMORY_SCOPE_AGENT);
    if (((o + 1u) & 7u) == 0u) {  // leaf-last of this round
      __builtin_amdgcn_fence(__ATOMIC_ACQ_REL, "agent");
      unsigned r = __hip_atomic_fetch_add(root, 1u, __ATOMIC_RELAXED, __HIP_MEMORY_SCOPE_AGENT);
      if (((r + 1u) & 7u) == 0u) {  // root-last: release everyone
        __builtin_amdgcn_fence(__ATOMIC_ACQ_REL, "agent");
        __hip_atomic_store(gen, g + 1u, __ATOMIC_RELEASE, __HIP_MEMORY_SCOPE_AGENT);
        releaser = true;
      }
    }
    if (!releaser) {
      int it = 0;
      for (;;) {
        if (__hip_atomic_load(gen, __ATOMIC_RELAXED, __HIP_MEMORY_SCOPE_AGENT) != g) break;
        __builtin_amdgcn_s_sleep(1);
        if ((++it & 1023) == 0) {  // safety valve: guaranteed-visible poll
          if (__hip_atomic_load(gen, __ATOMIC_ACQUIRE, __HIP_MEMORY_SCOPE_AGENT) != g) break;
        }
      }
    }
    __builtin_amdgcn_fence(__ATOMIC_ACQUIRE, "agent");  // invalidate stale L1/L2 once
  }
  __syncthreads();
}

__global__ void __launch_bounds__(256) rdec_kernel(Params p) {
  const int tid = threadIdx.x;
  const int bid = blockIdx.x;

  __shared__ float shh[512];
  __shared__ float shp[256], shm[256], shr[256], shtw[256];

  // ---- barrier state init handshake (ws is poisoned 0xAA each launch) ----
  if (bid == 0 && tid == 0) {
    for (int i = 1; i < 176; ++i)
      __hip_atomic_store(p.bar + i, 0u, __ATOMIC_RELAXED, __HIP_MEMORY_SCOPE_AGENT);
    __hip_atomic_store(p.bar, BAR_MAGIC, __ATOMIC_RELEASE, __HIP_MEMORY_SCOPE_AGENT);
  }
  if (tid == 0) {
    while (__hip_atomic_load(p.bar, __ATOMIC_ACQUIRE, __HIP_MEMORY_SCOPE_AGENT) != BAR_MAGIC)
      __builtin_amdgcn_s_sleep(1);
  }
  __syncthreads();

  // ---------------------------- P0: precompute ----------------------------
  if (bid < 32) {
    // fused: ali -> bf16 copy + amax/amin over t for each (b,e)
    const int b = bid, e = tid;
    const float* a0 = p.ali + b * 256 + e;
    unsigned short* ab = p.alib + b * 256 + e;
    float mx = -1e30f, mn = 1e30f;
    for (int t = 0; t < 256; ++t) {
      float a = a0[t * 8192];
      mx = fmaxf(mx, a);
      mn = fminf(mn, a);
      ab[t * 8192] = f2bfbits(a);
    }
    p.amax[b * 256 + e] = mx;
    p.amin[b * 256 + e] = mn;
  } else {
    int g = (bid - 32) * 256 + tid;  // 0..8191
    for (int i = g; i < 2252800; i += 8192) {
      if (i < 786432) {
        p.wihb[i] = __float2bfloat16(p.wih[i]);
      } else if (i < 1572864) {
        int j = i - 786432;
        p.whhb[j] = __float2bfloat16(p.whh[j]);
      } else if (i < 2097152) {
        int j = i - 1572864;
        int s = j >> 13;
        p.seqb[j] = (s == 0) ? __float2bfloat16(0.0f) : __float2bfloat16(p.dec[j - 8192]);
      } else if (i < 2170880) {
        int j = i - 2097152;
        int r = j / 768, c = j - r * 768;
        float v = (r < 80) ? p.wmel[j] : ((r == 80) ? p.wgate[c] : 0.0f);
        p.wmelgb[j] = __float2bfloat16(v);
      } else if (i < 2236416) {
        int j = i - 2170880;
        int kp = j >> 8, e = j & 255;
        unsigned lo = f2bfbits(p.watt[e * 512 + 2 * kp]);
        unsigned hi = f2bfbits(p.watt[e * 512 + 2 * kp + 1]);
        p.wattp[j] = lo | (hi << 16);
      } else {
        int j = i - 2236416;
        p.hf[j] = 0.0f;
        p.hbf[j] = __float2bfloat16(0.0f);  // hbf parity 0
      }
    }
  }
  gbar(p.bar, bid);

  // ------------------------------ main loop -------------------------------
  for (int s = 0; s <= 64; ++s) {
    // ---------------- PX: attention (blocks 0..31) ----------------
    if (s < 64 && bid < 32) {
      const int b = bid;
      // stage h[b,:] into LDS
      shh[tid] = p.hf[b * 512 + tid];
      shh[256 + tid] = p.hf[b * 512 + 256 + tid];
      __syncthreads();
      // pass 1: proj[e] (coalesced packed-bf16 W_att^T) + softmax denominator
      {
        const int e = tid;
        const unsigned* wp = p.wattp + e;
        float acc = 0.0f;
#pragma unroll 8
        for (int kp = 0; kp < 256; ++kp) {
          unsigned w = wp[kp * 256];
          acc = fmaf(__uint_as_float(w << 16), shh[2 * kp], acc);
          acc = fmaf(__uint_as_float(w & 0xffff0000u), shh[2 * kp + 1], acc);
        }
        float pe = acc;
        float m = (pe >= 0.0f) ? pe * p.amax[b * 256 + e] : pe * p.amin[b * 256 + e];
        float p2 = pe * LOG2E, m2 = m * LOG2E;
        shp[e] = p2;
        shm[e] = m2;
        const unsigned short* a0 = p.alib + b * 256 + e;
        float s0 = 0, s1 = 0, s2 = 0, s3 = 0;
        for (int t = 0; t < 256; t += 4) {
          s0 += exp2f(fmaf(btof(a0[(t + 0) * 8192]), p2, -m2));
          s1 += exp2f(fmaf(btof(a0[(t + 1) * 8192]), p2, -m2));
          s2 += exp2f(fmaf(btof(a0[(t + 2) * 8192]), p2, -m2));
          s3 += exp2f(fmaf(btof(a0[(t + 3) * 8192]), p2, -m2));
        }
        shr[e] = 1.0f / ((s0 + s1) + (s2 + s3));
      }
      __syncthreads();
      // pass 2: tw[t] = sum_e w[t,e]
      {
        const int t = tid;
        const bf8* arow = (const bf8*)(p.alib + (size_t)(t * 32 + b) * 256);
        float acc = 0.0f;
        for (int c = 0; c < 32; ++c) {
          bf8 av = arow[c];
#pragma unroll
          for (int j = 0; j < 8; ++j) {
            int e = c * 8 + j;
            acc += exp2f(fmaf(btof((unsigned short)av[j]), shp[e], -shm[e])) * shr[e];
          }
        }
        shtw[t] = acc;
      }
      __syncthreads();
      // pass 3: ctx[e] = sum_t tw[t]*a[t,b,e]  -> bf16 double buffer
      {
        const int e = tid;
        const unsigned short* a0 = p.alib + b * 256 + e;
        float c0 = 0, c1 = 0, c2 = 0, c3 = 0;
        for (int t = 0; t < 256; t += 4) {
          c0 += shtw[t + 0] * btof(a0[(t + 0) * 8192]);
          c1 += shtw[t + 1] * btof(a0[(t + 1) * 8192]);
          c2 += shtw[t + 2] * btof(a0[(t + 2) * 8192]);
          c3 += shtw[t + 3] * btof(a0[(t + 3) * 8192]);
        }
        p.ctxb[(s & 1) * 8192 + b * 256 + e] = __float2bfloat16((c0 + c1) + (c2 + c3));
      }
    } else if (s >= 1 && bid >= 32 && bid < 44 && tid < 64) {
      // ---------------- PX: mel/gate for step s-1 (MFMA) ----------------
      int tile = bid - 32;  // 12 tiles: mt(2) x nt(6)
      int mt = tile & 1, nt = tile >> 1;
      int l = tid, lm = l & 15, lq = l >> 4;
      const __hip_bfloat16* ctxp = p.ctxb + ((s - 1) & 1) * 8192;
      const __hip_bfloat16* hb = p.hbf + (s & 1) * 16384;
      int am = mt * 16 + lm;  // A row (batch)
      int bn = nt * 16 + lm;  // B row (output col of [96][768])
      f32x4 acc = {0.f, 0.f, 0.f, 0.f};
#pragma unroll
      for (int kt = 0; kt < 24; ++kt) {
        bf8 a = (kt < 8) ? ldfrag(ctxp + am * 256 + kt * 32 + lq * 8)
                         : ldfrag(hb + am * 512 + (kt - 8) * 32 + lq * 8);
        bf8 bb = ldfrag(p.wmelgb + bn * 768 + kt * 32 + lq * 8);
        acc = __builtin_amdgcn_mfma_f32_16x16x32_bf16(a, bb, acc, 0, 0, 0);
      }
      int t_out = s - 1;
#pragma unroll
      for (int r = 0; r < 4; ++r) {
        int b = mt * 16 + lq * 4 + r;  // D row = batch
        float v = acc[r];
        if (bn < 80)
          p.out[b * 5120 + bn * 64 + t_out] = v + p.bmel[bn];
        else if (bn == 80)
          p.out[163840 + b * 64 + t_out] = v + p.bgate[0];
      }
    }
    gbar(p.bar, bid);

    // ---------------- PY: fused gh + gi MFMA + GRU pointwise ----------------
    if (s < 64) {
      if (bid < 32 && tid < 128) {
        int mt = tid >> 6;  // two waves per block
        int l = tid & 63, lm = l & 15, lq = l >> 4;
        int am = mt * 16 + lm;      // A row (batch)
        int dcol = bid * 16 + lm;   // output d (D col) == W row offset
        const __hip_bfloat16* hb = p.hbf + (s & 1) * 16384;
        const __hip_bfloat16* ctxp = p.ctxb + (s & 1) * 8192;
        const __hip_bfloat16* seqp = p.seqb + s * 8192;
        f32x4 ar = {0.f, 0.f, 0.f, 0.f};
        f32x4 az = ar, ain = ar, ahn = ar;
        // gh = h @ W_hh^T  (K=512)
#pragma unroll
        for (int kt = 0; kt < 16; ++kt) {
          bf8 a = ldfrag(hb + am * 512 + kt * 32 + lq * 8);
          bf8 br = ldfrag(p.whhb + (dcol)*512 + kt * 32 + lq * 8);
          bf8 bz = ldfrag(p.whhb + (512 + dcol) * 512 + kt * 32 + lq * 8);
          bf8 bn = ldfrag(p.whhb + (1024 + dcol) * 512 + kt * 32 + lq * 8);
          ar = __builtin_amdgcn_mfma_f32_16x16x32_bf16(a, br, ar, 0, 0, 0);
          az = __builtin_amdgcn_mfma_f32_16x16x32_bf16(a, bz, az, 0, 0, 0);
          ahn = __builtin_amdgcn_mfma_f32_16x16x32_bf16(a, bn, ahn, 0, 0, 0);
        }
        // gi_dec = dec @ W_ih[:, 0:256]^T  (K=256)
#pragma unroll
        for (int kt = 0; kt < 8; ++kt) {
          bf8 a = ldfrag(seqp + am * 256 + kt * 32 + lq * 8);
          bf8 br = ldfrag(p.wihb + (dcol)*512 + kt * 32 + lq * 8);
          bf8 bz = ldfrag(p.wihb + (512 + dcol) * 512 + kt * 32 + lq * 8);
          bf8 bn = ldfrag(p.wihb + (1024 + dcol) * 512 + kt * 32 + lq * 8);
          ar = __builtin_amdgcn_mfma_f32_16x16x32_bf16(a, br, ar, 0, 0, 0);
          az = __builtin_amdgcn_mfma_f32_16x16x32_bf16(a, bz, az, 0, 0, 0);
          ain = __builtin_amdgcn_mfma_f32_16x16x32_bf16(a, bn, ain, 0, 0, 0);
        }
        // gi_ctx = ctx @ W_ih[:, 256:512]^T  (K=256)
#pragma unroll
        for (int kt = 0; kt < 8; ++kt) {
          bf8 a = ldfrag(ctxp + am * 256 + kt * 32 + lq * 8);
          bf8 br = ldfrag(p.wihb + (dcol)*512 + 256 + kt * 32 + lq * 8);
          bf8 bz = ldfrag(p.wihb + (512 + dcol) * 512 + 256 + kt * 32 + lq * 8);
          bf8 bn = ldfrag(p.wihb + (1024 + dcol) * 512 + 256 + kt * 32 + lq * 8);
          ar = __builtin_amdgcn_mfma_f32_16x16x32_bf16(a, br, ar, 0, 0, 0);
          az = __builtin_amdgcn_mfma_f32_16x16x32_bf16(a, bz, az, 0, 0, 0);
          ain = __builtin_amdgcn_mfma_f32_16x16x32_bf16(a, bn, ain, 0, 0, 0);
        }
        // GRU pointwise epilogue; D layout: row b=mt*16+lq*4+r, col d=dcol
        __hip_bfloat16* hbn = p.hbf + ((s + 1) & 1) * 16384;
#pragma unroll
        for (int r = 0; r < 4; ++r) {
          int b = mt * 16 + lq * 4 + r;
          float rg = sigm(ar[r]);
          float zg = sigm(az[r]);
          float nn = tanhfast(fmaf(rg, ahn[r], ain[r]));
          float ho = p.hf[b * 512 + dcol];
          float hn = fmaxf(0.0f, fmaf(zg, ho - nn, nn));  // relu((1-z)n+z*h)
          p.hf[b * 512 + dcol] = hn;
          hbn[b * 512 + dcol] = __float2bfloat16(hn);
        }
      }
      gbar(p.bar, bid);
    }
  }
}

extern "C" void kernel_launch(void* const* d_in, const int* in_sizes, int n_in,
                              void* d_out, int out_size, void* d_ws, size_t ws_size,
                              hipStream_t stream) {
  Params P;
  P.dec = (const float*)d_in[0];
  P.ali = (const float*)d_in[1];
  P.watt = (const float*)d_in[2];
  P.wih = (const float*)d_in[3];
  P.whh = (const float*)d_in[4];
  P.wmel = (const float*)d_in[5];
  P.bmel = (const float*)d_in[6];
  P.wgate = (const float*)d_in[7];
  P.bgate = (const float*)d_in[8];
  P.out = (float*)d_out;

  char* w = (char*)d_ws;
  size_t o = 0;
  auto nxt = [&](size_t b) {
    char* r = w + o;
    o += (b + 255) & ~(size_t)255;
    return r;
  };
  P.bar = (unsigned*)nxt(1024);
  P.amax = (float*)nxt(32 * 256 * 4);
  P.amin = (float*)nxt(32 * 256 * 4);
  P.wihb = (__hip_bfloat16*)nxt(1536 * 512 * 2);
  P.whhb = (__hip_bfloat16*)nxt(1536 * 512 * 2);
  P.wmelgb = (__hip_bfloat16*)nxt(96 * 768 * 2);
  P.seqb = (__hip_bfloat16*)nxt(64 * 32 * 256 * 2);
  P.hbf = (__hip_bfloat16*)nxt(2 * 32 * 512 * 2);
  P.ctxb = (__hip_bfloat16*)nxt(2 * 32 * 256 * 2);
  P.alib = (unsigned short*)nxt(256 * 32 * 256 * 2);
  P.wattp = (unsigned*)nxt(256 * 256 * 4);
  P.hf = (float*)nxt(32 * 512 * 4);

  void* args[] = {&P};
  hipError_t err = hipLaunchCooperativeKernel((void*)rdec_kernel, dim3(64), dim3(256),
                                              args, 0, stream);
  if (err != hipSuccess) {
    // fallback: plain launch (64 blocks on 256 CUs -> trivially co-resident)
    rdec_kernel<<<dim3(64), dim3(256), 0, stream>>>(P);
  }
}

// Round 3
// 3036.314 us; speedup vs baseline: 5.9390x; 1.0169x over previous
//
#include <hip/hip_runtime.h>
#include <hip/hip_bf16.h>

// ============================================================================
// RecurrentDecoder v3: 64-block persistent cooperative kernel.
// v2 -> v3: barrier spin now uses agent-scope atomic RMWs (coherence-point
// visible across XCDs) instead of relaxed loads (which read the stale local
// XCD L2 and only woke on the rare acquire safety poll ~ 21us/barrier).
//
//   P0  : blocks 0-31: ali->bf16 + amax/amin (fused);
//         blocks 32-63: bf16 weight copies, packed W_att^T, shifted dec, h=0.
//   loop s=0..64:
//     PX : blocks 0..31  -> per-b attention (proj, den, tw, ctx)   [s<64]
//          blocks 32..43 -> mel/gate MFMA for step s-1             [s>=1]
//     bar
//     PY : blocks 0..31 (2 waves) -> fused gh+gi MFMA + GRU pointwise [s<64]
//     bar
// ============================================================================

#define LOG2E 1.4426950408889634f
#define BAR_MAGIC 0x13572468u

typedef __attribute__((ext_vector_type(8))) short bf8;     // 8 x bf16 (4 VGPR)
typedef __attribute__((ext_vector_type(4))) float f32x4;

struct Params {
  const float* dec;    // [64][32][256]
  const float* ali;    // [256][32][256]
  const float* watt;   // [256][512]
  const float* wih;    // [1536][512]
  const float* whh;    // [1536][512]
  const float* wmel;   // [80][768]
  const float* bmel;   // [80]
  const float* wgate;  // [768]
  const float* bgate;  // [1]
  float* out;          // mel 32*80*64 then gate 32*64
  unsigned* bar;       // [0]=magic, [16]=gen, [32]=root, [48+16i]=leaf i
  float* amax;         // [32][256]
  float* amin;         // [32][256]
  __hip_bfloat16* wihb;    // [1536][512]
  __hip_bfloat16* whhb;    // [1536][512]
  __hip_bfloat16* wmelgb;  // [96][768] rows0..79=Wmel,80=Wgate,81..95=0
  __hip_bfloat16* seqb;    // [64][32][256] shifted dec inputs
  __hip_bfloat16* hbf;     // [2][32][512]
  __hip_bfloat16* ctxb;    // [2][32][256]
  unsigned short* alib;    // [256][32][256] bf16 raw bits
  unsigned* wattp;         // [256][256]: pair (k=2kp lo16, k=2kp+1 hi16) for e
  float* hf;               // [32][512]
};

__device__ __forceinline__ bf8 ldfrag(const __hip_bfloat16* p) {
  return *(const bf8*)p;
}
__device__ __forceinline__ float sigm(float x) {
  return 1.0f / (1.0f + exp2f(-x * LOG2E));
}
__device__ __forceinline__ float tanhfast(float x) {
  x = fminf(fmaxf(x, -15.0f), 15.0f);
  float e = exp2f(x * (2.0f * LOG2E));
  return (e - 1.0f) / (e + 1.0f);
}
__device__ __forceinline__ float btof(unsigned short v) {
  return __uint_as_float(((unsigned)v) << 16);
}
__device__ __forceinline__ unsigned short f2bfbits(float x) {
  __hip_bfloat16 h = __float2bfloat16(x);
  return *(unsigned short*)&h;
}
// Coherence-point read: agent-scope RMW bypasses the (non-coherent) local
// XCD L2, unlike a relaxed atomic load.
__device__ __forceinline__ unsigned crd(unsigned* p) {
  return __hip_atomic_fetch_add(p, 0u, __ATOMIC_RELAXED, __HIP_MEMORY_SCOPE_AGENT);
}

// Tree grid barrier: monotonic leaf/root counters, RMW-based spin (cross-XCD
// visible every poll), single acquire fence on wake. All 64 blocks call it.
__device__ __forceinline__ void gbar(unsigned* bar, int bid) {
  __syncthreads();  // intra-block + drains this block's stores toward L2
  if (threadIdx.x == 0) {
    unsigned* gen = bar + 16;
    unsigned* root = bar + 32;
    unsigned* leaf = bar + 48 + (bid & 7) * 16;
    unsigned g = crd(gen);
    __builtin_amdgcn_fence(__ATOMIC_RELEASE, "agent");  // publish block's writes
    bool releaser = false;
    unsigned o = __hip_atomic_fetch_add(leaf, 1u, __ATOMIC_RELAXED, __HIP_MEMORY_SCOPE_AGENT);
    if (((o + 1u) & 7u) == 0u) {  // leaf-last of this round
      unsigned r = __hip_atomic_fetch_add(root, 1u, __ATOMIC_RELAXED, __HIP_MEMORY_SCOPE_AGENT);
      if (((r + 1u) & 7u) == 0u) {  // root-last: release everyone (RMW-visible)
        __hip_atomic_fetch_add(gen, 1u, __ATOMIC_RELAXED, __HIP_MEMORY_SCOPE_AGENT);
        releaser = true;
      }
    }
    if (!releaser) {
      while (crd(gen) == g) __builtin_amdgcn_s_sleep(2);
    }
    __builtin_amdgcn_fence(__ATOMIC_ACQUIRE, "agent");  // invalidate stale lines once
  }
  __syncthreads();
}

__global__ void __launch_bounds__(256) rdec_kernel(Params p) {
  const int tid = threadIdx.x;
  const int bid = blockIdx.x;

  __shared__ float shh[512];
  __shared__ float shp[256], shm[256], shr[256], shtw[256];

  // ---- barrier state init handshake (ws is poisoned 0xAA each launch) ----
  if (bid == 0 && tid == 0) {
    for (int i = 1; i < 176; ++i)
      __hip_atomic_store(p.bar + i, 0u, __ATOMIC_RELAXED, __HIP_MEMORY_SCOPE_AGENT);
    __builtin_amdgcn_fence(__ATOMIC_RELEASE, "agent");
    __hip_atomic_fetch_add(p.bar, BAR_MAGIC, __ATOMIC_RELAXED, __HIP_MEMORY_SCOPE_AGENT);
  }
  if (tid == 0) {
    while (crd(p.bar) < BAR_MAGIC) __builtin_amdgcn_s_sleep(2);
    __builtin_amdgcn_fence(__ATOMIC_ACQUIRE, "agent");
  }
  __syncthreads();

  // ---------------------------- P0: precompute ----------------------------
  if (bid < 32) {
    // fused: ali -> bf16 copy + amax/amin over t for each (b,e)
    const int b = bid, e = tid;
    const float* a0 = p.ali + b * 256 + e;
    unsigned short* ab = p.alib + b * 256 + e;
    float mx = -1e30f, mn = 1e30f;
    for (int t = 0; t < 256; ++t) {
      float a = a0[t * 8192];
      mx = fmaxf(mx, a);
      mn = fminf(mn, a);
      ab[t * 8192] = f2bfbits(a);
    }
    p.amax[b * 256 + e] = mx;
    p.amin[b * 256 + e] = mn;
  } else {
    int g = (bid - 32) * 256 + tid;  // 0..8191
    for (int i = g; i < 2252800; i += 8192) {
      if (i < 786432) {
        p.wihb[i] = __float2bfloat16(p.wih[i]);
      } else if (i < 1572864) {
        int j = i - 786432;
        p.whhb[j] = __float2bfloat16(p.whh[j]);
      } else if (i < 2097152) {
        int j = i - 1572864;
        int s = j >> 13;
        p.seqb[j] = (s == 0) ? __float2bfloat16(0.0f) : __float2bfloat16(p.dec[j - 8192]);
      } else if (i < 2170880) {
        int j = i - 2097152;
        int r = j / 768, c = j - r * 768;
        float v = (r < 80) ? p.wmel[j] : ((r == 80) ? p.wgate[c] : 0.0f);
        p.wmelgb[j] = __float2bfloat16(v);
      } else if (i < 2236416) {
        int j = i - 2170880;
        int kp = j >> 8, e = j & 255;
        unsigned lo = f2bfbits(p.watt[e * 512 + 2 * kp]);
        unsigned hi = f2bfbits(p.watt[e * 512 + 2 * kp + 1]);
        p.wattp[j] = lo | (hi << 16);
      } else {
        int j = i - 2236416;
        p.hf[j] = 0.0f;
        p.hbf[j] = __float2bfloat16(0.0f);  // hbf parity 0
      }
    }
  }
  gbar(p.bar, bid);

  // ------------------------------ main loop -------------------------------
  for (int s = 0; s <= 64; ++s) {
    // ---------------- PX: attention (blocks 0..31) ----------------
    if (s < 64 && bid < 32) {
      const int b = bid;
      // stage h[b,:] into LDS
      shh[tid] = p.hf[b * 512 + tid];
      shh[256 + tid] = p.hf[b * 512 + 256 + tid];
      __syncthreads();
      // pass 1: proj[e] (coalesced packed-bf16 W_att^T) + softmax denominator
      {
        const int e = tid;
        const unsigned* wp = p.wattp + e;
        float acc = 0.0f;
#pragma unroll 8
        for (int kp = 0; kp < 256; ++kp) {
          unsigned w = wp[kp * 256];
          acc = fmaf(__uint_as_float(w << 16), shh[2 * kp], acc);
          acc = fmaf(__uint_as_float(w & 0xffff0000u), shh[2 * kp + 1], acc);
        }
        float pe = acc;
        float m = (pe >= 0.0f) ? pe * p.amax[b * 256 + e] : pe * p.amin[b * 256 + e];
        float p2 = pe * LOG2E, m2 = m * LOG2E;
        shp[e] = p2;
        shm[e] = m2;
        const unsigned short* a0 = p.alib + b * 256 + e;
        float s0 = 0, s1 = 0, s2 = 0, s3 = 0;
        for (int t = 0; t < 256; t += 4) {
          s0 += exp2f(fmaf(btof(a0[(t + 0) * 8192]), p2, -m2));
          s1 += exp2f(fmaf(btof(a0[(t + 1) * 8192]), p2, -m2));
          s2 += exp2f(fmaf(btof(a0[(t + 2) * 8192]), p2, -m2));
          s3 += exp2f(fmaf(btof(a0[(t + 3) * 8192]), p2, -m2));
        }
        shr[e] = 1.0f / ((s0 + s1) + (s2 + s3));
      }
      __syncthreads();
      // pass 2: tw[t] = sum_e w[t,e]
      {
        const int t = tid;
        const bf8* arow = (const bf8*)(p.alib + (size_t)(t * 32 + b) * 256);
        float acc = 0.0f;
        for (int c = 0; c < 32; ++c) {
          bf8 av = arow[c];
#pragma unroll
          for (int j = 0; j < 8; ++j) {
            int e = c * 8 + j;
            acc += exp2f(fmaf(btof((unsigned short)av[j]), shp[e], -shm[e])) * shr[e];
          }
        }
        shtw[t] = acc;
      }
      __syncthreads();
      // pass 3: ctx[e] = sum_t tw[t]*a[t,b,e]  -> bf16 double buffer
      {
        const int e = tid;
        const unsigned short* a0 = p.alib + b * 256 + e;
        float c0 = 0, c1 = 0, c2 = 0, c3 = 0;
        for (int t = 0; t < 256; t += 4) {
          c0 += shtw[t + 0] * btof(a0[(t + 0) * 8192]);
          c1 += shtw[t + 1] * btof(a0[(t + 1) * 8192]);
          c2 += shtw[t + 2] * btof(a0[(t + 2) * 8192]);
          c3 += shtw[t + 3] * btof(a0[(t + 3) * 8192]);
        }
        p.ctxb[(s & 1) * 8192 + b * 256 + e] = __float2bfloat16((c0 + c1) + (c2 + c3));
      }
    } else if (s >= 1 && bid >= 32 && bid < 44 && tid < 64) {
      // ---------------- PX: mel/gate for step s-1 (MFMA) ----------------
      int tile = bid - 32;  // 12 tiles: mt(2) x nt(6)
      int mt = tile & 1, nt = tile >> 1;
      int l = tid, lm = l & 15, lq = l >> 4;
      const __hip_bfloat16* ctxp = p.ctxb + ((s - 1) & 1) * 8192;
      const __hip_bfloat16* hb = p.hbf + (s & 1) * 16384;
      int am = mt * 16 + lm;  // A row (batch)
      int bn = nt * 16 + lm;  // B row (output col of [96][768])
      f32x4 acc = {0.f, 0.f, 0.f, 0.f};
#pragma unroll
      for (int kt = 0; kt < 24; ++kt) {
        bf8 a = (kt < 8) ? ldfrag(ctxp + am * 256 + kt * 32 + lq * 8)
                         : ldfrag(hb + am * 512 + (kt - 8) * 32 + lq * 8);
        bf8 bb = ldfrag(p.wmelgb + bn * 768 + kt * 32 + lq * 8);
        acc = __builtin_amdgcn_mfma_f32_16x16x32_bf16(a, bb, acc, 0, 0, 0);
      }
      int t_out = s - 1;
#pragma unroll
      for (int r = 0; r < 4; ++r) {
        int b = mt * 16 + lq * 4 + r;  // D row = batch
        float v = acc[r];
        if (bn < 80)
          p.out[b * 5120 + bn * 64 + t_out] = v + p.bmel[bn];
        else if (bn == 80)
          p.out[163840 + b * 64 + t_out] = v + p.bgate[0];
      }
    }
    gbar(p.bar, bid);

    // ---------------- PY: fused gh + gi MFMA + GRU pointwise ----------------
    if (s < 64) {
      if (bid < 32 && tid < 128) {
        int mt = tid >> 6;  // two waves per block
        int l = tid & 63, lm = l & 15, lq = l >> 4;
        int am = mt * 16 + lm;      // A row (batch)
        int dcol = bid * 16 + lm;   // output d (D col) == W row offset
        const __hip_bfloat16* hb = p.hbf + (s & 1) * 16384;
        const __hip_bfloat16* ctxp = p.ctxb + (s & 1) * 8192;
        const __hip_bfloat16* seqp = p.seqb + s * 8192;
        f32x4 ar = {0.f, 0.f, 0.f, 0.f};
        f32x4 az = ar, ain = ar, ahn = ar;
        // gh = h @ W_hh^T  (K=512)
#pragma unroll
        for (int kt = 0; kt < 16; ++kt) {
          bf8 a = ldfrag(hb + am * 512 + kt * 32 + lq * 8);
          bf8 br = ldfrag(p.whhb + (dcol)*512 + kt * 32 + lq * 8);
          bf8 bz = ldfrag(p.whhb + (512 + dcol) * 512 + kt * 32 + lq * 8);
          bf8 bn = ldfrag(p.whhb + (1024 + dcol) * 512 + kt * 32 + lq * 8);
          ar = __builtin_amdgcn_mfma_f32_16x16x32_bf16(a, br, ar, 0, 0, 0);
          az = __builtin_amdgcn_mfma_f32_16x16x32_bf16(a, bz, az, 0, 0, 0);
          ahn = __builtin_amdgcn_mfma_f32_16x16x32_bf16(a, bn, ahn, 0, 0, 0);
        }
        // gi_dec = dec @ W_ih[:, 0:256]^T  (K=256)
#pragma unroll
        for (int kt = 0; kt < 8; ++kt) {
          bf8 a = ldfrag(seqp + am * 256 + kt * 32 + lq * 8);
          bf8 br = ldfrag(p.wihb + (dcol)*512 + kt * 32 + lq * 8);
          bf8 bz = ldfrag(p.wihb + (512 + dcol) * 512 + kt * 32 + lq * 8);
          bf8 bn = ldfrag(p.wihb + (1024 + dcol) * 512 + kt * 32 + lq * 8);
          ar = __builtin_amdgcn_mfma_f32_16x16x32_bf16(a, br, ar, 0, 0, 0);
          az = __builtin_amdgcn_mfma_f32_16x16x32_bf16(a, bz, az, 0, 0, 0);
          ain = __builtin_amdgcn_mfma_f32_16x16x32_bf16(a, bn, ain, 0, 0, 0);
        }
        // gi_ctx = ctx @ W_ih[:, 256:512]^T  (K=256)
#pragma unroll
        for (int kt = 0; kt < 8; ++kt) {
          bf8 a = ldfrag(ctxp + am * 256 + kt * 32 + lq * 8);
          bf8 br = ldfrag(p.wihb + (dcol)*512 + 256 + kt * 32 + lq * 8);
          bf8 bz = ldfrag(p.wihb + (512 + dcol) * 512 + 256 + kt * 32 + lq * 8);
          bf8 bn = ldfrag(p.wihb + (1024 + dcol) * 512 + 256 + kt * 32 + lq * 8);
          ar = __builtin_amdgcn_mfma_f32_16x16x32_bf16(a, br, ar, 0, 0, 0);
          az = __builtin_amdgcn_mfma_f32_16x16x32_bf16(a, bz, az, 0, 0, 0);
          ain = __builtin_amdgcn_mfma_f32_16x16x32_bf16(a, bn, ain, 0, 0, 0);
        }
        // GRU pointwise epilogue; D layout: row b=mt*16+lq*4+r, col d=dcol
        __hip_bfloat16* hbn = p.hbf + ((s + 1) & 1) * 16384;
#pragma unroll
        for (int r = 0; r < 4; ++r) {
          int b = mt * 16 + lq * 4 + r;
          float rg = sigm(ar[r]);
          float zg = sigm(az[r]);
          float nn = tanhfast(fmaf(rg, ahn[r], ain[r]));
          float ho = p.hf[b * 512 + dcol];
          float hn = fmaxf(0.0f, fmaf(zg, ho - nn, nn));  // relu((1-z)n+z*h)
          p.hf[b * 512 + dcol] = hn;
          hbn[b * 512 + dcol] = __float2bfloat16(hn);
        }
      }
      gbar(p.bar, bid);
    }
  }
}

extern "C" void kernel_launch(void* const* d_in, const int* in_sizes, int n_in,
                              void* d_out, int out_size, void* d_ws, size_t ws_size,
                              hipStream_t stream) {
  Params P;
  P.dec = (const float*)d_in[0];
  P.ali = (const float*)d_in[1];
  P.watt = (const float*)d_in[2];
  P.wih = (const float*)d_in[3];
  P.whh = (const float*)d_in[4];
  P.wmel = (const float*)d_in[5];
  P.bmel = (const float*)d_in[6];
  P.wgate = (const float*)d_in[7];
  P.bgate = (const float*)d_in[8];
  P.out = (float*)d_out;

  char* w = (char*)d_ws;
  size_t o = 0;
  auto nxt = [&](size_t b) {
    char* r = w + o;
    o += (b + 255) & ~(size_t)255;
    return r;
  };
  P.bar = (unsigned*)nxt(1024);
  P.amax = (float*)nxt(32 * 256 * 4);
  P.amin = (float*)nxt(32 * 256 * 4);
  P.wihb = (__hip_bfloat16*)nxt(1536 * 512 * 2);
  P.whhb = (__hip_bfloat16*)nxt(1536 * 512 * 2);
  P.wmelgb = (__hip_bfloat16*)nxt(96 * 768 * 2);
  P.seqb = (__hip_bfloat16*)nxt(64 * 32 * 256 * 2);
  P.hbf = (__hip_bfloat16*)nxt(2 * 32 * 512 * 2);
  P.ctxb = (__hip_bfloat16*)nxt(2 * 32 * 256 * 2);
  P.alib = (unsigned short*)nxt(256 * 32 * 256 * 2);
  P.wattp = (unsigned*)nxt(256 * 256 * 4);
  P.hf = (float*)nxt(32 * 512 * 4);

  void* args[] = {&P};
  hipError_t err = hipLaunchCooperativeKernel((void*)rdec_kernel, dim3(64), dim3(256),
                                              args, 0, stream);
  if (err != hipSuccess) {
    // fallback: plain launch (64 blocks on 256 CUs -> trivially co-resident)
    rdec_kernel<<<dim3(64), dim3(256), 0, stream>>>(P);
  }
}

// Round 4
// 1747.568 us; speedup vs baseline: 10.3188x; 1.7375x over previous
//
#include <hip/hip_runtime.h>
#include <hip/hip_bf16.h>

// ============================================================================
// RecurrentDecoder v4: 66-block persistent cooperative kernel, resident data.
//  - att blocks 0..31 (one per batch b): alignment slice in LDS (133 KB),
//    W_att^T columns in VGPRs (128/thread), 512 threads, split-passes.
//  - GRU blocks 32..63 (one per 16-col slice of D): W_hh/W_ih B-fragments
//    resident in VGPRs; gh in phase X (only needs h), gi+pointwise in Y.
//  - mel blocks 64..65: W_mel/gate fragments resident; runs in X on (s-1).
//  Per step: X[att(s) | gh(s) | mel(s-1)]  bar  Y[gi(s)+GRU pointwise]  bar
// ============================================================================

#define LOG2E 1.4426950408889634f
#define BAR_MAGIC 0x13572468u
#define SMEM_BYTES 146432

typedef __attribute__((ext_vector_type(8))) short bf8;
typedef __attribute__((ext_vector_type(4))) float f32x4;

#if __has_builtin(__builtin_amdgcn_exp2f)
#define EX2(x) __builtin_amdgcn_exp2f(x)
#else
#define EX2(x) exp2f(x)
#endif

#define MFMA16(a, b, c) __builtin_amdgcn_mfma_f32_16x16x32_bf16(a, b, c, 0, 0, 0)

struct Params {
  const float* dec;    // [64][32][256]
  const float* ali;    // [256][32][256]
  const float* watt;   // [256][512]
  const float* wih;    // [1536][512]
  const float* whh;    // [1536][512]
  const float* wmel;   // [80][768]
  const float* bmel;   // [80]
  const float* wgate;  // [768]
  const float* bgate;  // [1]
  float* out;          // mel 32*80*64 then gate 32*64
  unsigned* bar;       // [0]=magic, [16]=gen, [32]=root, [48+16i]=leaf i
  __hip_bfloat16* wihb;    // [1536][512]
  __hip_bfloat16* whhb;    // [1536][512]
  __hip_bfloat16* wmelgb;  // [96][768] rows0..79=Wmel,80=Wgate,81..95=0
  __hip_bfloat16* seqb;    // [64][32][256] shifted dec inputs
  __hip_bfloat16* hbf;     // [2][32][512]
  __hip_bfloat16* ctxb;    // [2][32][256]
  unsigned* wattp;         // [256][256]: kp-major packed bf16 pairs of W_att[e]
  float* hf;               // [32][512]
};

__device__ __forceinline__ bf8 ldfrag(const __hip_bfloat16* p) {
  return *(const bf8*)p;
}
__device__ __forceinline__ float sigm(float x) {
  return 1.0f / (1.0f + EX2(-x * LOG2E));
}
__device__ __forceinline__ float tanhfast(float x) {
  x = fminf(fmaxf(x, -15.0f), 15.0f);
  float e = EX2(x * (2.0f * LOG2E));
  return (e - 1.0f) / (e + 1.0f);
}
__device__ __forceinline__ float btof(unsigned short v) {
  return __uint_as_float(((unsigned)v) << 16);
}
__device__ __forceinline__ unsigned short f2bfbits(float x) {
  __hip_bfloat16 h = __float2bfloat16(x);
  return *(unsigned short*)&h;
}
__device__ __forceinline__ unsigned crd(unsigned* p) {
  return __hip_atomic_fetch_add(p, 0u, __ATOMIC_RELAXED, __HIP_MEMORY_SCOPE_AGENT);
}

// Tree grid barrier for 66 blocks: monotonic leaf/root counters, RMW-visible,
// one acquire fence on wake. leaf l=bid&7; leaves 0,1 have 9 members, rest 8.
__device__ __forceinline__ void gbar(unsigned* bar, int bid) {
  __syncthreads();
  if (threadIdx.x == 0) {
    unsigned* gen = bar + 16;
    unsigned* root = bar + 32;
    const int lf = bid & 7;
    unsigned* leaf = bar + 48 + lf * 16;
    const unsigned ltarget = (lf < 2) ? 9u : 8u;
    unsigned g = crd(gen);
    __builtin_amdgcn_fence(__ATOMIC_RELEASE, "agent");
    bool releaser = false;
    unsigned o = __hip_atomic_fetch_add(leaf, 1u, __ATOMIC_RELAXED, __HIP_MEMORY_SCOPE_AGENT);
    if ((o + 1u) % ltarget == 0u) {
      unsigned r = __hip_atomic_fetch_add(root, 1u, __ATOMIC_RELAXED, __HIP_MEMORY_SCOPE_AGENT);
      if (((r + 1u) & 7u) == 0u) {
        __hip_atomic_fetch_add(gen, 1u, __ATOMIC_RELAXED, __HIP_MEMORY_SCOPE_AGENT);
        releaser = true;
      }
    }
    if (!releaser) {
      while (crd(gen) == g) __builtin_amdgcn_s_sleep(2);
    }
    __builtin_amdgcn_fence(__ATOMIC_ACQUIRE, "agent");
  }
  __syncthreads();
}

// P0a conversion work for blocks 32..65 (wid in [0, 34*512))
__device__ __forceinline__ void p0a_worker(const Params& p, int wid) {
  for (int i = wid; i < 2252800; i += 17408) {
    if (i < 786432) {
      p.wihb[i] = __float2bfloat16(p.wih[i]);
    } else if (i < 1572864) {
      int j = i - 786432;
      p.whhb[j] = __float2bfloat16(p.whh[j]);
    } else if (i < 2097152) {
      int j = i - 1572864;
      int s = j >> 13;
      p.seqb[j] = (s == 0) ? __float2bfloat16(0.0f) : __float2bfloat16(p.dec[j - 8192]);
    } else if (i < 2170880) {
      int j = i - 2097152;
      int r = j / 768, c = j - r * 768;
      float v = (r < 80) ? p.wmel[j] : ((r == 80) ? p.wgate[c] : 0.0f);
      p.wmelgb[j] = __float2bfloat16(v);
    } else if (i < 2236416) {
      int j = i - 2170880;
      int kp = j >> 8, e = j & 255;
      unsigned lo = f2bfbits(p.watt[e * 512 + 2 * kp]);
      unsigned hi = f2bfbits(p.watt[e * 512 + 2 * kp + 1]);
      p.wattp[j] = lo | (hi << 16);
    } else {
      int j = i - 2236416;
      p.hf[j] = 0.0f;
      p.hbf[j] = __float2bfloat16(0.0f);  // hbf parity 0
    }
  }
}

__global__ void __launch_bounds__(512, 2) rdec_kernel(Params p) {
  const int tid = threadIdx.x;
  const int bid = blockIdx.x;
  extern __shared__ char smem[];

  // ---- barrier state init handshake (ws poisoned 0xAA each launch) ----
  if (bid == 0 && tid == 0) {
    for (int i = 1; i < 176; ++i)
      __hip_atomic_store(p.bar + i, 0u, __ATOMIC_RELAXED, __HIP_MEMORY_SCOPE_AGENT);
    __builtin_amdgcn_fence(__ATOMIC_RELEASE, "agent");
    __hip_atomic_fetch_add(p.bar, BAR_MAGIC, __ATOMIC_RELAXED, __HIP_MEMORY_SCOPE_AGENT);
  }
  if (tid == 0) {
    while (crd(p.bar) < BAR_MAGIC) __builtin_amdgcn_s_sleep(2);
    __builtin_amdgcn_fence(__ATOMIC_ACQUIRE, "agent");
  }
  __syncthreads();

  if (bid < 32) {
    // ============================ ATT path ============================
    const int b = bid;
    unsigned short* alds = (unsigned short*)smem;  // [256][260] bf16
    float* shh = (float*)(smem + 256 * 260 * 2);   // 512
    float* shp = shh + 512;                        // 256
    float* shr = shp + 256;                        // 256
    float* shtw = shr + 256;                       // 256
    float* pA = shtw + 256;                        // 512
    float* pB = pA + 512;
    float* pC = pB + 512;
    float* pD = pC + 512;
    const int e = tid & 255, th = tid >> 8;
    // P0a: ali -> LDS bf16 (this block's batch slice, loaded once)
    for (int i = tid; i < 65536; i += 512) {
      int t = i >> 8, ee = i & 255;
      alds[t * 260 + ee] = f2bfbits(p.ali[t * 8192 + b * 256 + ee]);
    }
    gbar(p.bar, bid);
    // P0b: resident W_att^T column slice (kp-half per th)
    unsigned wr[128];
#pragma unroll
    for (int i = 0; i < 128; ++i) wr[i] = p.wattp[(th * 128 + i) * 256 + e];

    for (int s = 0; s < 64; ++s) {
      shh[tid] = p.hf[b * 512 + tid];
      __syncthreads();
      // proj partial (k-split by th), from registers
      {
        float acc = 0.f;
        const float2* h2 = (const float2*)shh;
#pragma unroll
        for (int i = 0; i < 128; ++i) {
          unsigned w = wr[i];
          float2 hv = h2[th * 128 + i];
          acc = fmaf(__uint_as_float(w << 16), hv.x, acc);
          acc = fmaf(__uint_as_float(w & 0xffff0000u), hv.y, acc);
        }
        pA[th * 256 + e] = acc;
      }
      __syncthreads();
      const float p2 = (pA[e] + pA[256 + e]) * LOG2E;
      if (tid < 256) shp[e] = p2;
      // softmax denominator partial (t-split by th); no max-sub (|arg|<75)
      {
        float d0 = 0.f, d1 = 0.f;
        const int t0 = th * 128;
#pragma unroll 4
        for (int t = t0; t < t0 + 128; t += 2) {
          d0 += EX2(btof(alds[(t + 0) * 260 + e]) * p2);
          d1 += EX2(btof(alds[(t + 1) * 260 + e]) * p2);
        }
        pB[th * 256 + e] = d0 + d1;
      }
      __syncthreads();
      if (tid < 256) shr[e] = 1.0f / (pB[e] + pB[256 + e]);
      __syncthreads();
      // tw partial (e-split by th)
      {
        const int t = tid & 255;
        const ushort4* row = (const ushort4*)(alds + t * 260 + th * 128);
        float acc = 0.f;
#pragma unroll 4
        for (int q = 0; q < 32; ++q) {
          ushort4 v = row[q];
          int eb = th * 128 + q * 4;
          acc += EX2(btof(v.x) * shp[eb + 0]) * shr[eb + 0];
          acc += EX2(btof(v.y) * shp[eb + 1]) * shr[eb + 1];
          acc += EX2(btof(v.z) * shp[eb + 2]) * shr[eb + 2];
          acc += EX2(btof(v.w) * shp[eb + 3]) * shr[eb + 3];
        }
        pC[th * 256 + t] = acc;
      }
      __syncthreads();
      if (tid < 256) shtw[tid] = pC[tid] + pC[256 + tid];
      __syncthreads();
      // ctx partial (t-split by th)
      {
        float c0 = 0.f, c1 = 0.f;
        const int t0 = th * 128;
#pragma unroll 4
        for (int t = t0; t < t0 + 128; t += 2) {
          c0 += shtw[t + 0] * btof(alds[(t + 0) * 260 + e]);
          c1 += shtw[t + 1] * btof(alds[(t + 1) * 260 + e]);
        }
        pD[th * 256 + e] = c0 + c1;
      }
      __syncthreads();
      if (tid < 256)
        p.ctxb[(s & 1) * 8192 + b * 256 + e] = __float2bfloat16(pD[e] + pD[256 + e]);
      gbar(p.bar, bid);  // end X
      gbar(p.bar, bid);  // end Y (idle)
    }
  } else if (bid < 64) {
    // ============================ GRU path ============================
    const int dt = bid - 32;  // dcol tile: d in [dt*16, dt*16+16)
    const int wv = tid >> 6;
    const bool act = wv < 6;
    const int l = tid & 63, lm = l & 15, lq = l >> 4;
    const int g = wv % 3, mt = wv / 3;  // gate, batch-half
    const int am = mt * 16 + lm;
    const int brow = g * 512 + dt * 16 + lm;
    float* pw = (float*)smem;  // [8][16][17] f32
    p0a_worker(p, (bid - 32) * 512 + tid);
    gbar(p.bar, bid);
    // P0b: resident B-fragments (W_hh K=512, W_ih dec K=256, W_ih ctx K=256)
    bf8 WH[16], WD[8], WC[8];
    if (act) {
#pragma unroll
      for (int kt = 0; kt < 16; ++kt) WH[kt] = ldfrag(p.whhb + brow * 512 + kt * 32 + lq * 8);
#pragma unroll
      for (int kt = 0; kt < 8; ++kt) WD[kt] = ldfrag(p.wihb + brow * 512 + kt * 32 + lq * 8);
#pragma unroll
      for (int kt = 0; kt < 8; ++kt) WC[kt] = ldfrag(p.wihb + brow * 512 + 256 + kt * 32 + lq * 8);
    }
    for (int s = 0; s < 64; ++s) {
      // X: gh = h(s) @ W_hh^T (only needs h)
      f32x4 acc = {0.f, 0.f, 0.f, 0.f};
      if (act) {
        const __hip_bfloat16* hb = p.hbf + (s & 1) * 16384;
#pragma unroll
        for (int kt = 0; kt < 16; ++kt) {
          bf8 a = ldfrag(hb + am * 512 + kt * 32 + lq * 8);
          acc = MFMA16(a, WH[kt], acc);
        }
      }
      gbar(p.bar, bid);
      // Y: gi (dec + ctx) and pointwise
      if (act) {
        const __hip_bfloat16* seqp = p.seqb + s * 8192;
        const __hip_bfloat16* ctxp = p.ctxb + (s & 1) * 8192;
        f32x4 gi = {0.f, 0.f, 0.f, 0.f};
#pragma unroll
        for (int kt = 0; kt < 8; ++kt) {
          bf8 a = ldfrag(seqp + am * 256 + kt * 32 + lq * 8);
          gi = MFMA16(a, WD[kt], gi);
        }
#pragma unroll
        for (int kt = 0; kt < 8; ++kt) {
          bf8 a = ldfrag(ctxp + am * 256 + kt * 32 + lq * 8);
          gi = MFMA16(a, WC[kt], gi);
        }
        if (g < 2) {
#pragma unroll
          for (int r = 0; r < 4; ++r) pw[(wv * 16 + lq * 4 + r) * 17 + lm] = acc[r] + gi[r];
        } else {
          // n-gate: keep hidden (hn) and input (inn) parts separate
#pragma unroll
          for (int r = 0; r < 4; ++r) pw[(wv * 16 + lq * 4 + r) * 17 + lm] = acc[r];
#pragma unroll
          for (int r = 0; r < 4; ++r) pw[((6 + mt) * 16 + lq * 4 + r) * 17 + lm] = gi[r];
        }
      }
      __syncthreads();
      // pointwise: 512 threads = 32 b x 16 d
      {
        const int bb = tid >> 4, dl = tid & 15;
        const int mtb = bb >> 4, bl = bb & 15;
        float rg = sigm(pw[((mtb * 3 + 0) * 16 + bl) * 17 + dl]);
        float zg = sigm(pw[((mtb * 3 + 1) * 16 + bl) * 17 + dl]);
        float hn = pw[((mtb * 3 + 2) * 16 + bl) * 17 + dl];
        float inn = pw[((6 + mtb) * 16 + bl) * 17 + dl];
        float nn = tanhfast(fmaf(rg, hn, inn));
        const int d = dt * 16 + dl;
        float ho = p.hf[bb * 512 + d];
        float hnew = fmaxf(0.0f, fmaf(zg, ho - nn, nn));  // relu((1-z)n+z*h)
        p.hf[bb * 512 + d] = hnew;
        p.hbf[((s + 1) & 1) * 16384 + bb * 512 + d] = __float2bfloat16(hnew);
      }
      gbar(p.bar, bid);
    }
  } else {
    // ============================ MEL path ============================
    const int mt = bid - 64;  // batch half
    const int wv = tid >> 6;
    const bool act = wv < 6;
    const int l = tid & 63, lm = l & 15, lq = l >> 4;
    const int nt = wv;
    const int am = mt * 16 + lm, bn = nt * 16 + lm;
    p0a_worker(p, (bid - 32) * 512 + tid);
    gbar(p.bar, bid);
    bf8 WM[24];
    float bias = 0.f;
    if (act) {
#pragma unroll
      for (int kt = 0; kt < 24; ++kt) WM[kt] = ldfrag(p.wmelgb + bn * 768 + kt * 32 + lq * 8);
      bias = (bn < 80) ? p.bmel[bn] : ((bn == 80) ? p.bgate[0] : 0.f);
    }
    for (int s = 0; s < 64; ++s) {
      if (s >= 1 && act) {
        const int tau = s - 1;
        const __hip_bfloat16* ctxp = p.ctxb + (tau & 1) * 8192;
        const __hip_bfloat16* hb = p.hbf + ((tau + 1) & 1) * 16384;
        f32x4 acc = {0.f, 0.f, 0.f, 0.f};
#pragma unroll
        for (int kt = 0; kt < 24; ++kt) {
          bf8 a = (kt < 8) ? ldfrag(ctxp + am * 256 + kt * 32 + lq * 8)
                           : ldfrag(hb + am * 512 + (kt - 8) * 32 + lq * 8);
          acc = MFMA16(a, WM[kt], acc);
        }
#pragma unroll
        for (int r = 0; r < 4; ++r) {
          int bb = mt * 16 + lq * 4 + r;
          float v = acc[r] + bias;
          if (bn < 80)
            p.out[bb * 5120 + bn * 64 + tau] = v;
          else if (bn == 80)
            p.out[163840 + bb * 64 + tau] = v;
        }
      }
      gbar(p.bar, bid);
      gbar(p.bar, bid);
    }
    // final mel for step 63 (h(64), ctx(63) both ready after last barrier)
    if (act) {
      const int tau = 63;
      const __hip_bfloat16* ctxp = p.ctxb + (tau & 1) * 8192;
      const __hip_bfloat16* hb = p.hbf + ((tau + 1) & 1) * 16384;
      f32x4 acc = {0.f, 0.f, 0.f, 0.f};
#pragma unroll
      for (int kt = 0; kt < 24; ++kt) {
        bf8 a = (kt < 8) ? ldfrag(ctxp + am * 256 + kt * 32 + lq * 8)
                         : ldfrag(hb + am * 512 + (kt - 8) * 32 + lq * 8);
        acc = MFMA16(a, WM[kt], acc);
      }
#pragma unroll
      for (int r = 0; r < 4; ++r) {
        int bb = mt * 16 + lq * 4 + r;
        float v = acc[r] + bias;
        if (bn < 80)
          p.out[bb * 5120 + bn * 64 + tau] = v;
        else if (bn == 80)
          p.out[163840 + bb * 64 + tau] = v;
      }
    }
  }
}

extern "C" void kernel_launch(void* const* d_in, const int* in_sizes, int n_in,
                              void* d_out, int out_size, void* d_ws, size_t ws_size,
                              hipStream_t stream) {
  Params P;
  P.dec = (const float*)d_in[0];
  P.ali = (const float*)d_in[1];
  P.watt = (const float*)d_in[2];
  P.wih = (const float*)d_in[3];
  P.whh = (const float*)d_in[4];
  P.wmel = (const float*)d_in[5];
  P.bmel = (const float*)d_in[6];
  P.wgate = (const float*)d_in[7];
  P.bgate = (const float*)d_in[8];
  P.out = (float*)d_out;

  char* w = (char*)d_ws;
  size_t o = 0;
  auto nxt = [&](size_t b) {
    char* r = w + o;
    o += (b + 255) & ~(size_t)255;
    return r;
  };
  P.bar = (unsigned*)nxt(1024);
  P.wihb = (__hip_bfloat16*)nxt(1536 * 512 * 2);
  P.whhb = (__hip_bfloat16*)nxt(1536 * 512 * 2);
  P.wmelgb = (__hip_bfloat16*)nxt(96 * 768 * 2);
  P.seqb = (__hip_bfloat16*)nxt(64 * 32 * 256 * 2);
  P.hbf = (__hip_bfloat16*)nxt(2 * 32 * 512 * 2);
  P.ctxb = (__hip_bfloat16*)nxt(2 * 32 * 256 * 2);
  P.wattp = (unsigned*)nxt(256 * 256 * 4);
  P.hf = (float*)nxt(32 * 512 * 4);

  (void)hipFuncSetAttribute((const void*)rdec_kernel,
                            hipFuncAttributeMaxDynamicSharedMemorySize, SMEM_BYTES);

  void* args[] = {&P};
  hipError_t err = hipLaunchCooperativeKernel((void*)rdec_kernel, dim3(66), dim3(512),
                                              args, SMEM_BYTES, stream);
  if (err != hipSuccess) {
    // fallback: plain launch (66 blocks on 256 CUs -> trivially co-resident)
    rdec_kernel<<<dim3(66), dim3(512), SMEM_BYTES, stream>>>(P);
  }
}